// Round 8
// baseline (3634.348 us; speedup 1.0000x reference)
//
#include <hip/hip_runtime.h>

#define NN 100000
#define NE 1600000
#define DIM 128
#define NT 13            // src tiles: src>>13 -> 8192 rows = 2 MB bf16 per tile (fits 4 MB L2)
#define SH 13
#define LEN (NN * NT)    // bucket counters, tile-major: idx = tt*NN + dst
#define NB_SCAN ((LEN + 1023) / 1024)

typedef __attribute__((ext_vector_type(8))) short short8;
typedef __attribute__((ext_vector_type(4))) float f4;
typedef __attribute__((ext_vector_type(4))) unsigned u4;

__device__ __forceinline__ unsigned short f2bf(float f){
  unsigned x = __float_as_uint(f);
  x += 0x7fffu + ((x >> 16) & 1u);
  return (unsigned short)(x >> 16);
}
__device__ __forceinline__ unsigned pack2(float lo, float hi){
  return ((unsigned)f2bf(hi) << 16) | (unsigned)f2bf(lo);
}
__device__ __forceinline__ float blo(unsigned u){ return __uint_as_float(u << 16); }
__device__ __forceinline__ float bhi(unsigned u){ return __uint_as_float(u & 0xffff0000u); }

// ---------------- fallback sentinel (ws too small diagnostic) ----------------
__global__ void k_sentinel(float* __restrict__ out, int n){
  int i = blockIdx.x * blockDim.x + threadIdx.x;
  if (i < n) out[i] = 12345.0f;
}

// ---------------- x fp32 -> bf16x2 (each thread: 8 floats -> 16 B out) ------
__global__ void k_cvt(const float* __restrict__ x, unsigned* __restrict__ xb){
  int i = blockIdx.x * blockDim.x + threadIdx.x;   // i < NN*16
  if (i >= NN * 16) return;
  f4 a = ((const f4*)x)[2 * i];
  f4 b = ((const f4*)x)[2 * i + 1];
  u4 o;
  o[0] = pack2(a[0], a[1]); o[1] = pack2(a[2], a[3]);
  o[2] = pack2(b[0], b[1]); o[3] = pack2(b[2], b[3]);
  ((u4*)xb)[i] = o;
}

// ---------------- bucketed CSR build (tile-major) ----------------
__global__ void k_hist(const int* __restrict__ src, const int* __restrict__ dst,
                       int* __restrict__ cnt){
  int i = blockIdx.x * blockDim.x + threadIdx.x;
  if (i < NE) atomicAdd(&cnt[(src[i] >> SH) * NN + dst[i]], 1);
}

__global__ void k_deg(const int* __restrict__ cnt, int* __restrict__ deg){
  int i = blockIdx.x * blockDim.x + threadIdx.x;
  if (i < NN){
    int s = 0;
    #pragma unroll
    for (int tt = 0; tt < NT; ++tt) s += cnt[tt * NN + i];
    deg[i] = s;
  }
}

__global__ void k_bsum(const int* __restrict__ cnt, int* __restrict__ bsum, int len){
  __shared__ int sh[256];
  int t = threadIdx.x, b = blockIdx.x;
  int base = b * 1024 + t * 4;
  int s = 0;
  #pragma unroll
  for (int j = 0; j < 4; ++j){ int i = base + j; if (i < len) s += cnt[i]; }
  sh[t] = s; __syncthreads();
  for (int off = 128; off > 0; off >>= 1){
    if (t < off) sh[t] += sh[t + off];
    __syncthreads();
  }
  if (t == 0) bsum[b] = sh[0];
}

__global__ void k_scanp(const int* __restrict__ bsum, int* __restrict__ boff, int nb){
  __shared__ int sh[256];
  int t = threadIdx.x;
  int chunk = (nb + 255) / 256;
  int s = 0;
  for (int j = 0; j < chunk; ++j){ int i = t * chunk + j; if (i < nb) s += bsum[i]; }
  sh[t] = s; __syncthreads();
  int tin = s;
  for (int off = 1; off < 256; off <<= 1){
    int u = (t >= off) ? sh[t - off] : 0;
    __syncthreads();
    sh[t] += u;
    __syncthreads();
  }
  int run = sh[t] - tin;
  for (int j = 0; j < chunk; ++j){
    int i = t * chunk + j;
    if (i < nb){ boff[i] = run; run += bsum[i]; }
  }
}

__global__ void k_scanf(const int* __restrict__ cnt, const int* __restrict__ boff,
                        int* __restrict__ rp, int* __restrict__ pos, int len){
  __shared__ int sh[256];
  int t = threadIdx.x, b = blockIdx.x;
  int base = b * 1024 + t * 4;
  int c[4]; int s = 0;
  #pragma unroll
  for (int j = 0; j < 4; ++j){ int i = base + j; c[j] = (i < len) ? cnt[i] : 0; s += c[j]; }
  sh[t] = s; __syncthreads();
  int tin = s;
  for (int off = 1; off < 256; off <<= 1){
    int u = (t >= off) ? sh[t - off] : 0;
    __syncthreads();
    sh[t] += u;
    __syncthreads();
  }
  int run = boff[b] + sh[t] - tin;
  #pragma unroll
  for (int j = 0; j < 4; ++j){
    int i = base + j;
    if (i < len){
      rp[i] = run; pos[i] = run; run += c[j];
      if (i == len - 1) rp[len] = run;
    }
  }
}

// pack src (17b) | (dst&7)<<20 — wave row-groups are 8-aligned
__global__ void k_scatter(const int* __restrict__ src, const int* __restrict__ dst,
                          int* __restrict__ pos, int* __restrict__ ss){
  int i = blockIdx.x * blockDim.x + threadIdx.x;
  if (i < NE){
    int s = src[i], d = dst[i];
    int p = atomicAdd(&pos[(s >> SH) * NN + d], 1);
    ss[p] = s | ((d & 7) << 20);
  }
}

// ---------------- W packing: fp32 -> bf16 MFMA B-fragment order ----------------
template<int NB16>
__global__ void k_pack(const float* __restrict__ Wl,
                       const float* __restrict__ Wr,
                       unsigned short* __restrict__ Bp){
  constexpr int DOUT = NB16 * 16;
  int idx = blockIdx.x * blockDim.x + threadIdx.x;
  if (idx >= 8 * NB16 * 64) return;
  int lane = idx & 63;
  int nb = (idx >> 6) % NB16;
  int ks = idx / (64 * NB16);
  int n = nb * 16 + (lane & 15);
  int k0 = ks * 32 + (lane >> 4) * 8;
  short8 v;
  #pragma unroll
  for (int j = 0; j < 8; ++j){
    int k = k0 + j;
    float w = (k < 128) ? Wl[k * DOUT + n] : Wr[(k - 128) * DOUT + n];
    v[j] = (short)f2bf(w);
  }
  ((short8*)Bp)[idx] = v;
}

// ---------------- fused tiled mean-aggregate + dual-GEMM (+BN+ReLU) ----------------
// Phase 1: per (wave, tile) one contiguous ss range for the wave's 8 rows.
// Branch-free edge body: gather + 2x ds_add_f32 into per-wave LDS fp32 tile
// (stride-2 dword -> 2-way bank aliasing = free). Phase 2: MFMA 16x16x32 bf16.
template<int NB16, bool DO_BN>
__global__ __launch_bounds__(256)
void k_fused(const unsigned* __restrict__ Xb,
             const int* __restrict__ rp2, const int* __restrict__ ss,
             const int* __restrict__ deg,
             const unsigned short* __restrict__ Bp,
             const float* __restrict__ bias,
             const float* __restrict__ bg, const float* __restrict__ bb,
             const float* __restrict__ bm, const float* __restrict__ bv,
             unsigned short* __restrict__ OutB, float* __restrict__ OutF){
  constexpr int DOUT = NB16 * 16;
  constexpr int NBW = NB16 / 4;
  __shared__ float smF[32][132];      // fp32 accumulators (rows wave-private)
  __shared__ unsigned smA[32][68];    // bf16x2 GEMM staging
  const int t = threadIdx.x;
  const int lane = t & 63;
  const int wv = t >> 6;
  const int m0 = blockIdx.x * 32;
  const int row0 = m0 + wv * 8;

  // ---- init accumulators (wave-private rows; barrier for safety) ----
  #pragma unroll
  for (int rr = 0; rr < 8; ++rr){
    smF[wv * 8 + rr][lane] = 0.f;
    smF[wv * 8 + rr][lane + 64] = 0.f;
  }
  __syncthreads();

  float* const base = &smF[wv * 8][0];

  // ---- phase 1: tiled mean aggregation, branch-free ds_add_f32 ----
  for (int tt = 0; tt < NT; ++tt){
    int beg = __builtin_amdgcn_readfirstlane(rp2[tt * NN + row0]);
    int end = __builtin_amdgcn_readfirstlane(rp2[tt * NN + row0 + 8]);
    int e = beg;
    for (; e + 4 <= end; e += 4){
      int e0 = ss[e], e1 = ss[e + 1], e2 = ss[e + 2], e3 = ss[e + 3];
      unsigned u0 = Xb[(size_t)(e0 & 0xFFFFF) * 64 + lane];
      unsigned u1 = Xb[(size_t)(e1 & 0xFFFFF) * 64 + lane];
      unsigned u2 = Xb[(size_t)(e2 & 0xFFFFF) * 64 + lane];
      unsigned u3 = Xb[(size_t)(e3 & 0xFFFFF) * 64 + lane];
      float* p0 = base + (e0 >> 20) * 132 + 2 * lane;
      float* p1 = base + (e1 >> 20) * 132 + 2 * lane;
      float* p2 = base + (e2 >> 20) * 132 + 2 * lane;
      float* p3 = base + (e3 >> 20) * 132 + 2 * lane;
      atomicAdd(p0, blo(u0)); atomicAdd(p0 + 1, bhi(u0));
      atomicAdd(p1, blo(u1)); atomicAdd(p1 + 1, bhi(u1));
      atomicAdd(p2, blo(u2)); atomicAdd(p2 + 1, bhi(u2));
      atomicAdd(p3, blo(u3)); atomicAdd(p3 + 1, bhi(u3));
    }
    for (; e < end; ++e){
      int e0 = ss[e];
      unsigned u0 = Xb[(size_t)(e0 & 0xFFFFF) * 64 + lane];
      float* p0 = base + (e0 >> 20) * 132 + 2 * lane;
      atomicAdd(p0, blo(u0)); atomicAdd(p0 + 1, bhi(u0));
    }
  }

  // ---- mean + pack to bf16x2 staging ----
  #pragma unroll
  for (int rr = 0; rr < 8; ++rr){
    int d = deg[row0 + rr];
    float inv = (d > 0) ? 1.f / (float)d : 0.f;
    float lo = smF[wv * 8 + rr][2 * lane] * inv;
    float hi = smF[wv * 8 + rr][2 * lane + 1] * inv;
    smA[wv * 8 + rr][lane] = pack2(lo, hi);
  }
  __syncthreads();

  // ---- phase 2: dual GEMM (K 0..127 = mean@Wl from LDS, 128..255 = h@Wr) ----
  const int q = lane >> 4, lr = lane & 15;
  const short8* pb = (const short8*)Bp + lane;
  f4 acc[2][NBW];
  #pragma unroll
  for (int g = 0; g < 2; ++g)
    #pragma unroll
    for (int j = 0; j < NBW; ++j)
      acc[g][j] = (f4){0.f, 0.f, 0.f, 0.f};

  const unsigned* sA0 = &smA[lr][0];
  const unsigned* sA1 = &smA[lr + 16][0];
  #pragma unroll
  for (int ks = 0; ks < 4; ++ks){
    short8 a0 = *(const short8*)(sA0 + q*4 + ks*16);
    short8 a1 = *(const short8*)(sA1 + q*4 + ks*16);
    #pragma unroll
    for (int j = 0; j < NBW; ++j){
      int nb = wv * NBW + j;
      short8 b = pb[(ks * NB16 + nb) * 64];
      acc[0][j] = __builtin_amdgcn_mfma_f32_16x16x32_bf16(a0, b, acc[0][j], 0, 0, 0);
      acc[1][j] = __builtin_amdgcn_mfma_f32_16x16x32_bf16(a1, b, acc[1][j], 0, 0, 0);
    }
  }
  #pragma unroll
  for (int ks = 0; ks < 4; ++ks){
    short8 a0 = *(const short8*)(Xb + (size_t)(m0 + lr) * 64 + q*4 + ks*16);
    short8 a1 = *(const short8*)(Xb + (size_t)(m0 + lr + 16) * 64 + q*4 + ks*16);
    #pragma unroll
    for (int j = 0; j < NBW; ++j){
      int nb = wv * NBW + j;
      short8 b = pb[((4 + ks) * NB16 + nb) * 64];
      acc[0][j] = __builtin_amdgcn_mfma_f32_16x16x32_bf16(a0, b, acc[0][j], 0, 0, 0);
      acc[1][j] = __builtin_amdgcn_mfma_f32_16x16x32_bf16(a1, b, acc[1][j], 0, 0, 0);
    }
  }

  // ---- epilogue: C/D layout col=lane&15, row=(lane>>4)*4+reg ----
  #pragma unroll
  for (int j = 0; j < NBW; ++j){
    int col = (wv * NBW + j) * 16 + lr;
    float S = 1.f, T;
    if constexpr (DO_BN){
      float s = bg[col] * rsqrtf(bv[col] + 1e-5f);
      S = s;
      T = (bias[col] - bm[col]) * s + bb[col];
    } else {
      T = bias[col];
    }
    #pragma unroll
    for (int r = 0; r < 4; ++r){
      int row = m0 + q * 4 + r;
      float y0 = acc[0][j][r] * S + T;
      float y1 = acc[1][j][r] * S + T;
      if constexpr (DO_BN){
        y0 = y0 > 0.f ? y0 : 0.f;
        y1 = y1 > 0.f ? y1 : 0.f;
        OutB[(size_t)row * DOUT + col] = f2bf(y0);
        OutB[(size_t)(row + 16) * DOUT + col] = f2bf(y1);
      } else {
        OutF[(size_t)row * DOUT + col] = y0;
        OutF[(size_t)(row + 16) * DOUT + col] = y1;
      }
    }
  }
}

extern "C" void kernel_launch(void* const* d_in, const int* in_sizes, int n_in,
                              void* d_out, int out_size, void* d_ws, size_t ws_size,
                              hipStream_t stream){
  const float* x = (const float*)d_in[0];
  const int* ei = (const int*)d_in[1];
  const float* Wl0 = (const float*)d_in[2];
  const float* Wr0 = (const float*)d_in[3];
  const float* bl0 = (const float*)d_in[4];
  const float* Wl1 = (const float*)d_in[5];
  const float* Wr1 = (const float*)d_in[6];
  const float* bl1 = (const float*)d_in[7];
  const float* Wl2 = (const float*)d_in[8];
  const float* Wr2 = (const float*)d_in[9];
  const float* bl2 = (const float*)d_in[10];
  const float* g0 = (const float*)d_in[11];
  const float* b0 = (const float*)d_in[12];
  const float* bm0 = (const float*)d_in[13];
  const float* bv0 = (const float*)d_in[14];
  const float* g1 = (const float*)d_in[15];
  const float* b1 = (const float*)d_in[16];
  const float* bm1 = (const float*)d_in[17];
  const float* bv1 = (const float*)d_in[18];

  // ws (~48.2 MB <= 58 MB proven): ALL scratch in ws now; d_out holds only h1
  // (written by L0, read by L1, dead before L2 writes final output).
  const size_t REQUIRED = 48200000;
  if (ws_size < REQUIRED){
    k_sentinel<<<(out_size + 255) / 256, 256, 0, stream>>>((float*)d_out, out_size);
    return;
  }

  char* w = (char*)d_ws;
  size_t off = 0;
  auto alloc = [&](size_t bytes) -> char* {
    char* p = w + off; off = (off + bytes + 255) & ~(size_t)255; return p;
  };
  int* rp2 = (int*)alloc((size_t)(LEN + 1) * 4);
  int* ss  = (int*)alloc((size_t)NE * 4);
  unsigned short* bp0 = (unsigned short*)alloc(8 * 8 * 64 * 8 * 2);
  unsigned short* bp1 = (unsigned short*)alloc(8 * 8 * 64 * 8 * 2);
  unsigned short* bp2 = (unsigned short*)alloc(8 * 4 * 64 * 8 * 2);
  unsigned* xb = (unsigned*)alloc((size_t)NN * 64 * 4);   // bf16x2 x; reused as h2
  unsigned short* h2 = (unsigned short*)xb;
  int* cnt2 = (int*)alloc((size_t)LEN * 4);
  int* pos2 = (int*)alloc((size_t)LEN * 4);
  int* deg  = (int*)alloc((size_t)NN * 4);
  int* bsum = (int*)alloc(NB_SCAN * 4);
  int* boff = (int*)alloc(NB_SCAN * 4);
  unsigned short* h1 = (unsigned short*)d_out;            // 25.6 MB, exactly d_out

  const int* srcI = ei;
  const int* dstI = ei + NE;

  hipMemsetAsync(cnt2, 0, (size_t)LEN * 4, stream);
  k_cvt<<<(NN * 16 + 255) / 256, 256, 0, stream>>>(x, xb);
  k_hist<<<(NE + 255) / 256, 256, 0, stream>>>(srcI, dstI, cnt2);
  k_deg<<<(NN + 255) / 256, 256, 0, stream>>>(cnt2, deg);
  k_bsum<<<NB_SCAN, 256, 0, stream>>>(cnt2, bsum, LEN);
  k_scanp<<<1, 256, 0, stream>>>(bsum, boff, NB_SCAN);
  k_scanf<<<NB_SCAN, 256, 0, stream>>>(cnt2, boff, rp2, pos2, LEN);
  k_scatter<<<(NE + 255) / 256, 256, 0, stream>>>(srcI, dstI, pos2, ss);
  k_pack<8><<<16, 256, 0, stream>>>(Wl0, Wr0, bp0);
  k_pack<8><<<16, 256, 0, stream>>>(Wl1, Wr1, bp1);
  k_pack<4><<<8, 256, 0, stream>>>(Wl2, Wr2, bp2);

  k_fused<8, true ><<<3125, 256, 0, stream>>>(xb, rp2, ss, deg, bp0,
      bl0, g0, b0, bm0, bv0, h1, nullptr);
  k_fused<8, true ><<<3125, 256, 0, stream>>>((const unsigned*)h1, rp2, ss, deg, bp1,
      bl1, g1, b1, bm1, bv1, h2, nullptr);
  k_fused<4, false><<<3125, 256, 0, stream>>>((const unsigned*)h2, rp2, ss, deg, bp2,
      bl2, nullptr, nullptr, nullptr, nullptr, nullptr, (float*)d_out);
}

// Round 9
// 609.238 us; speedup vs baseline: 5.9654x; 5.9654x over previous
//
#include <hip/hip_runtime.h>

#define NN 100000
#define NE 1600000
#define DIM 128
#define NT 13            // src tiles: src>>13 -> 8192 rows = 2 MB bf16 per tile (fits 4 MB L2)
#define SH 13
#define LEN (NN * NT)    // bucket counters, tile-major: idx = tt*NN + dst
#define NB_SCAN ((LEN + 1023) / 1024)
#define FST 140          // smF row stride (dwords): 16B-aligned, 2-way banks only

typedef __attribute__((ext_vector_type(8))) short short8;
typedef __attribute__((ext_vector_type(4))) float f4;
typedef __attribute__((ext_vector_type(4))) unsigned u4;

__device__ __forceinline__ unsigned short f2bf(float f){
  unsigned x = __float_as_uint(f);
  x += 0x7fffu + ((x >> 16) & 1u);
  return (unsigned short)(x >> 16);
}
__device__ __forceinline__ unsigned pack2(float lo, float hi){
  return ((unsigned)f2bf(hi) << 16) | (unsigned)f2bf(lo);
}
__device__ __forceinline__ float blo(unsigned u){ return __uint_as_float(u << 16); }
__device__ __forceinline__ float bhi(unsigned u){ return __uint_as_float(u & 0xffff0000u); }
__device__ __forceinline__ short8 cvt8(f4 a, f4 b){
  short8 r;
  #pragma unroll
  for (int j = 0; j < 4; ++j){ r[j] = (short)f2bf(a[j]); r[j+4] = (short)f2bf(b[j]); }
  return r;
}

// ---------------- fallback sentinel (ws too small diagnostic) ----------------
__global__ void k_sentinel(float* __restrict__ out, int n){
  int i = blockIdx.x * blockDim.x + threadIdx.x;
  if (i < n) out[i] = 12345.0f;
}

// ---------------- x fp32 -> bf16x2 (each thread: 8 floats -> 16 B out) ------
__global__ void k_cvt(const float* __restrict__ x, unsigned* __restrict__ xb){
  int i = blockIdx.x * blockDim.x + threadIdx.x;   // i < NN*16
  if (i >= NN * 16) return;
  f4 a = ((const f4*)x)[2 * i];
  f4 b = ((const f4*)x)[2 * i + 1];
  u4 o;
  o[0] = pack2(a[0], a[1]); o[1] = pack2(a[2], a[3]);
  o[2] = pack2(b[0], b[1]); o[3] = pack2(b[2], b[3]);
  ((u4*)xb)[i] = o;
}

// ---------------- bucketed CSR build (tile-major) ----------------
__global__ void k_hist(const int* __restrict__ src, const int* __restrict__ dst,
                       int* __restrict__ cnt){
  int i = blockIdx.x * blockDim.x + threadIdx.x;
  if (i < NE) atomicAdd(&cnt[(src[i] >> SH) * NN + dst[i]], 1);
}

__global__ void k_deg(const int* __restrict__ cnt, int* __restrict__ deg){
  int i = blockIdx.x * blockDim.x + threadIdx.x;
  if (i < NN){
    int s = 0;
    #pragma unroll
    for (int tt = 0; tt < NT; ++tt) s += cnt[tt * NN + i];
    deg[i] = s;
  }
}

__global__ void k_bsum(const int* __restrict__ cnt, int* __restrict__ bsum, int len){
  __shared__ int sh[256];
  int t = threadIdx.x, b = blockIdx.x;
  int base = b * 1024 + t * 4;
  int s = 0;
  #pragma unroll
  for (int j = 0; j < 4; ++j){ int i = base + j; if (i < len) s += cnt[i]; }
  sh[t] = s; __syncthreads();
  for (int off = 128; off > 0; off >>= 1){
    if (t < off) sh[t] += sh[t + off];
    __syncthreads();
  }
  if (t == 0) bsum[b] = sh[0];
}

__global__ void k_scanp(const int* __restrict__ bsum, int* __restrict__ boff, int nb){
  __shared__ int sh[256];
  int t = threadIdx.x;
  int chunk = (nb + 255) / 256;
  int s = 0;
  for (int j = 0; j < chunk; ++j){ int i = t * chunk + j; if (i < nb) s += bsum[i]; }
  sh[t] = s; __syncthreads();
  int tin = s;
  for (int off = 1; off < 256; off <<= 1){
    int u = (t >= off) ? sh[t - off] : 0;
    __syncthreads();
    sh[t] += u;
    __syncthreads();
  }
  int run = sh[t] - tin;
  for (int j = 0; j < chunk; ++j){
    int i = t * chunk + j;
    if (i < nb){ boff[i] = run; run += bsum[i]; }
  }
}

__global__ void k_scanf(const int* __restrict__ cnt, const int* __restrict__ boff,
                        int* __restrict__ rp, int* __restrict__ pos, int len){
  __shared__ int sh[256];
  int t = threadIdx.x, b = blockIdx.x;
  int base = b * 1024 + t * 4;
  int c[4]; int s = 0;
  #pragma unroll
  for (int j = 0; j < 4; ++j){ int i = base + j; c[j] = (i < len) ? cnt[i] : 0; s += c[j]; }
  sh[t] = s; __syncthreads();
  int tin = s;
  for (int off = 1; off < 256; off <<= 1){
    int u = (t >= off) ? sh[t - off] : 0;
    __syncthreads();
    sh[t] += u;
    __syncthreads();
  }
  int run = boff[b] + sh[t] - tin;
  #pragma unroll
  for (int j = 0; j < 4; ++j){
    int i = base + j;
    if (i < len){
      rp[i] = run; pos[i] = run; run += c[j];
      if (i == len - 1) rp[len] = run;
    }
  }
}

// pack src (17b) | (dst&7)<<20 — wave row-groups are 8-aligned
__global__ void k_scatter(const int* __restrict__ src, const int* __restrict__ dst,
                          int* __restrict__ pos, int* __restrict__ ss){
  int i = blockIdx.x * blockDim.x + threadIdx.x;
  if (i < NE){
    int s = src[i], d = dst[i];
    int p = atomicAdd(&pos[(s >> SH) * NN + d], 1);
    ss[p] = s | ((d & 7) << 20);
  }
}

// ---------------- W packing: fp32 -> bf16 MFMA B-fragment order ----------------
template<int NB16>
__global__ void k_pack(const float* __restrict__ Wl,
                       const float* __restrict__ Wr,
                       unsigned short* __restrict__ Bp){
  constexpr int DOUT = NB16 * 16;
  int idx = blockIdx.x * blockDim.x + threadIdx.x;
  if (idx >= 8 * NB16 * 64) return;
  int lane = idx & 63;
  int nb = (idx >> 6) % NB16;
  int ks = idx / (64 * NB16);
  int n = nb * 16 + (lane & 15);
  int k0 = ks * 32 + (lane >> 4) * 8;
  short8 v;
  #pragma unroll
  for (int j = 0; j < 8; ++j){
    int k = k0 + j;
    float w = (k < 128) ? Wl[k * DOUT + n] : Wr[(k - 128) * DOUT + n];
    v[j] = (short)f2bf(w);
  }
  ((short8*)Bp)[idx] = v;
}

// ---------------- fused tiled mean-aggregate + dual-GEMM (+BN+ReLU) ----------------
// Phase 1: per (wave,tile) one contiguous ss range; tags monotone (CSR sorted by
// dst within tile) -> running cx/cy accumulators, flush to wave-private LDS rows
// only on tag change (plain ds r/w, NOT per-edge RMW — r8 lesson). 8-deep gather
// batches; all 26 range bounds prefetched via 2 lane-indexed loads.
template<int NB16, bool DO_BN>
__global__ __launch_bounds__(256)
void k_fused(const unsigned* __restrict__ Xb,
             const int* __restrict__ rp2, const int* __restrict__ ss,
             const int* __restrict__ deg,
             const unsigned short* __restrict__ Bp,
             const float* __restrict__ bias,
             const float* __restrict__ bg, const float* __restrict__ bb,
             const float* __restrict__ bm, const float* __restrict__ bv,
             unsigned short* __restrict__ OutB, float* __restrict__ OutF){
  constexpr int DOUT = NB16 * 16;
  constexpr int NBW = NB16 / 4;
  __shared__ float smF[32][FST];
  const int t = threadIdx.x;
  const int lane = t & 63;
  const int wv = t >> 6;
  const int m0 = blockIdx.x * 32;
  const int row0 = m0 + wv * 8;

  // zero accumulators
  for (int i = t; i < 32 * FST; i += 256) (&smF[0][0])[i] = 0.f;
  __syncthreads();

  float* const base = &smF[wv * 8][0];

  // prefetch all 13 range bounds (one latency)
  int bAll = (lane < NT) ? rp2[lane * NN + row0] : 0;
  int eAll = (lane < NT) ? rp2[lane * NN + row0 + 8] : 0;

  float cx = 0.f, cy = 0.f;
  int cur = 0;

  #define CONS(g, u) {                                        \
    int _r = (g) >> 20;                                       \
    if (_r != cur){                                           \
      float* _p = base + cur * FST + 2 * lane;                \
      _p[0] += cx; _p[1] += cy;                               \
      cx = 0.f; cy = 0.f; cur = _r;                           \
    }                                                         \
    cx += blo(u); cy += bhi(u);                               \
  }

  for (int tt = 0; tt < NT; ++tt){
    int e   = __shfl(bAll, tt);
    int end = __shfl(eAll, tt);
    for (; e + 8 <= end; e += 8){
      int g0 = __builtin_amdgcn_readfirstlane(ss[e]);
      int g1 = __builtin_amdgcn_readfirstlane(ss[e + 1]);
      int g2 = __builtin_amdgcn_readfirstlane(ss[e + 2]);
      int g3 = __builtin_amdgcn_readfirstlane(ss[e + 3]);
      int g4 = __builtin_amdgcn_readfirstlane(ss[e + 4]);
      int g5 = __builtin_amdgcn_readfirstlane(ss[e + 5]);
      int g6 = __builtin_amdgcn_readfirstlane(ss[e + 6]);
      int g7 = __builtin_amdgcn_readfirstlane(ss[e + 7]);
      unsigned u0 = Xb[(size_t)(g0 & 0xFFFFF) * 64 + lane];
      unsigned u1 = Xb[(size_t)(g1 & 0xFFFFF) * 64 + lane];
      unsigned u2 = Xb[(size_t)(g2 & 0xFFFFF) * 64 + lane];
      unsigned u3 = Xb[(size_t)(g3 & 0xFFFFF) * 64 + lane];
      unsigned u4_ = Xb[(size_t)(g4 & 0xFFFFF) * 64 + lane];
      unsigned u5 = Xb[(size_t)(g5 & 0xFFFFF) * 64 + lane];
      unsigned u6 = Xb[(size_t)(g6 & 0xFFFFF) * 64 + lane];
      unsigned u7 = Xb[(size_t)(g7 & 0xFFFFF) * 64 + lane];
      CONS(g0, u0); CONS(g1, u1); CONS(g2, u2); CONS(g3, u3);
      CONS(g4, u4_); CONS(g5, u5); CONS(g6, u6); CONS(g7, u7);
    }
    for (; e + 4 <= end; e += 4){
      int g0 = __builtin_amdgcn_readfirstlane(ss[e]);
      int g1 = __builtin_amdgcn_readfirstlane(ss[e + 1]);
      int g2 = __builtin_amdgcn_readfirstlane(ss[e + 2]);
      int g3 = __builtin_amdgcn_readfirstlane(ss[e + 3]);
      unsigned u0 = Xb[(size_t)(g0 & 0xFFFFF) * 64 + lane];
      unsigned u1 = Xb[(size_t)(g1 & 0xFFFFF) * 64 + lane];
      unsigned u2 = Xb[(size_t)(g2 & 0xFFFFF) * 64 + lane];
      unsigned u3 = Xb[(size_t)(g3 & 0xFFFFF) * 64 + lane];
      CONS(g0, u0); CONS(g1, u1); CONS(g2, u2); CONS(g3, u3);
    }
    for (; e < end; ++e){
      int g0 = __builtin_amdgcn_readfirstlane(ss[e]);
      unsigned u0 = Xb[(size_t)(g0 & 0xFFFFF) * 64 + lane];
      CONS(g0, u0);
    }
  }
  { // final flush
    float* p = base + cur * FST + 2 * lane;
    p[0] += cx; p[1] += cy;
  }
  #undef CONS
  __syncthreads();

  // normalize: mean = sum / deg  (thread t: row t>>3, cols (t&7)*16..+15)
  {
    int row = t >> 3;
    int d = deg[m0 + row];
    float inv = (d > 0) ? 1.f / (float)d : 0.f;
    float* pr = &smF[row][(t & 7) * 16];
    #pragma unroll
    for (int i = 0; i < 16; ++i) pr[i] *= inv;
  }
  __syncthreads();

  // ---- phase 2: dual GEMM (K 0..127 = mean@Wl from LDS fp32, 128..255 = h@Wr) ----
  const int q = lane >> 4, lr = lane & 15;
  const short8* pb = (const short8*)Bp + lane;
  f4 acc[2][NBW];
  #pragma unroll
  for (int g = 0; g < 2; ++g)
    #pragma unroll
    for (int j = 0; j < NBW; ++j)
      acc[g][j] = (f4){0.f, 0.f, 0.f, 0.f};

  #pragma unroll
  for (int ks = 0; ks < 4; ++ks){
    const float* r0 = &smF[lr][ks * 32 + q * 8];
    const float* r1 = &smF[lr + 16][ks * 32 + q * 8];
    short8 a0 = cvt8(*(const f4*)r0, *(const f4*)(r0 + 4));
    short8 a1 = cvt8(*(const f4*)r1, *(const f4*)(r1 + 4));
    #pragma unroll
    for (int j = 0; j < NBW; ++j){
      int nb = wv * NBW + j;
      short8 b = pb[(ks * NB16 + nb) * 64];
      acc[0][j] = __builtin_amdgcn_mfma_f32_16x16x32_bf16(a0, b, acc[0][j], 0, 0, 0);
      acc[1][j] = __builtin_amdgcn_mfma_f32_16x16x32_bf16(a1, b, acc[1][j], 0, 0, 0);
    }
  }
  #pragma unroll
  for (int ks = 0; ks < 4; ++ks){
    short8 a0 = *(const short8*)(Xb + (size_t)(m0 + lr) * 64 + q*4 + ks*16);
    short8 a1 = *(const short8*)(Xb + (size_t)(m0 + lr + 16) * 64 + q*4 + ks*16);
    #pragma unroll
    for (int j = 0; j < NBW; ++j){
      int nb = wv * NBW + j;
      short8 b = pb[((4 + ks) * NB16 + nb) * 64];
      acc[0][j] = __builtin_amdgcn_mfma_f32_16x16x32_bf16(a0, b, acc[0][j], 0, 0, 0);
      acc[1][j] = __builtin_amdgcn_mfma_f32_16x16x32_bf16(a1, b, acc[1][j], 0, 0, 0);
    }
  }

  // ---- epilogue: C/D layout col=lane&15, row=(lane>>4)*4+reg ----
  #pragma unroll
  for (int j = 0; j < NBW; ++j){
    int col = (wv * NBW + j) * 16 + lr;
    float S = 1.f, T;
    if constexpr (DO_BN){
      float s = bg[col] * rsqrtf(bv[col] + 1e-5f);
      S = s;
      T = (bias[col] - bm[col]) * s + bb[col];
    } else {
      T = bias[col];
    }
    #pragma unroll
    for (int r = 0; r < 4; ++r){
      int row = m0 + q * 4 + r;
      float y0 = acc[0][j][r] * S + T;
      float y1 = acc[1][j][r] * S + T;
      if constexpr (DO_BN){
        y0 = y0 > 0.f ? y0 : 0.f;
        y1 = y1 > 0.f ? y1 : 0.f;
        OutB[(size_t)row * DOUT + col] = f2bf(y0);
        OutB[(size_t)(row + 16) * DOUT + col] = f2bf(y1);
      } else {
        OutF[(size_t)row * DOUT + col] = y0;
        OutF[(size_t)(row + 16) * DOUT + col] = y1;
      }
    }
  }
}

extern "C" void kernel_launch(void* const* d_in, const int* in_sizes, int n_in,
                              void* d_out, int out_size, void* d_ws, size_t ws_size,
                              hipStream_t stream){
  const float* x = (const float*)d_in[0];
  const int* ei = (const int*)d_in[1];
  const float* Wl0 = (const float*)d_in[2];
  const float* Wr0 = (const float*)d_in[3];
  const float* bl0 = (const float*)d_in[4];
  const float* Wl1 = (const float*)d_in[5];
  const float* Wr1 = (const float*)d_in[6];
  const float* bl1 = (const float*)d_in[7];
  const float* Wl2 = (const float*)d_in[8];
  const float* Wr2 = (const float*)d_in[9];
  const float* bl2 = (const float*)d_in[10];
  const float* g0 = (const float*)d_in[11];
  const float* b0 = (const float*)d_in[12];
  const float* bm0 = (const float*)d_in[13];
  const float* bv0 = (const float*)d_in[14];
  const float* g1 = (const float*)d_in[15];
  const float* b1 = (const float*)d_in[16];
  const float* bm1 = (const float*)d_in[17];
  const float* bv1 = (const float*)d_in[18];

  const size_t REQUIRED = 48200000;
  if (ws_size < REQUIRED){
    k_sentinel<<<(out_size + 255) / 256, 256, 0, stream>>>((float*)d_out, out_size);
    return;
  }

  char* w = (char*)d_ws;
  size_t off = 0;
  auto alloc = [&](size_t bytes) -> char* {
    char* p = w + off; off = (off + bytes + 255) & ~(size_t)255; return p;
  };
  int* rp2 = (int*)alloc((size_t)(LEN + 1) * 4);
  int* ss  = (int*)alloc((size_t)NE * 4);
  unsigned short* bp0 = (unsigned short*)alloc(8 * 8 * 64 * 8 * 2);
  unsigned short* bp1 = (unsigned short*)alloc(8 * 8 * 64 * 8 * 2);
  unsigned short* bp2 = (unsigned short*)alloc(8 * 4 * 64 * 8 * 2);
  unsigned* xb = (unsigned*)alloc((size_t)NN * 64 * 4);   // bf16x2 x; reused as h2
  unsigned short* h2 = (unsigned short*)xb;
  int* cnt2 = (int*)alloc((size_t)LEN * 4);
  int* pos2 = (int*)alloc((size_t)LEN * 4);
  int* deg  = (int*)alloc((size_t)NN * 4);
  int* bsum = (int*)alloc(NB_SCAN * 4);
  int* boff = (int*)alloc(NB_SCAN * 4);
  unsigned short* h1 = (unsigned short*)d_out;            // 25.6 MB, exactly d_out

  const int* srcI = ei;
  const int* dstI = ei + NE;

  hipMemsetAsync(cnt2, 0, (size_t)LEN * 4, stream);
  k_cvt<<<(NN * 16 + 255) / 256, 256, 0, stream>>>(x, xb);
  k_hist<<<(NE + 255) / 256, 256, 0, stream>>>(srcI, dstI, cnt2);
  k_deg<<<(NN + 255) / 256, 256, 0, stream>>>(cnt2, deg);
  k_bsum<<<NB_SCAN, 256, 0, stream>>>(cnt2, bsum, LEN);
  k_scanp<<<1, 256, 0, stream>>>(bsum, boff, NB_SCAN);
  k_scanf<<<NB_SCAN, 256, 0, stream>>>(cnt2, boff, rp2, pos2, LEN);
  k_scatter<<<(NE + 255) / 256, 256, 0, stream>>>(srcI, dstI, pos2, ss);
  k_pack<8><<<16, 256, 0, stream>>>(Wl0, Wr0, bp0);
  k_pack<8><<<16, 256, 0, stream>>>(Wl1, Wr1, bp1);
  k_pack<4><<<8, 256, 0, stream>>>(Wl2, Wr2, bp2);

  k_fused<8, true ><<<3125, 256, 0, stream>>>(xb, rp2, ss, deg, bp0,
      bl0, g0, b0, bm0, bv0, h1, nullptr);
  k_fused<8, true ><<<3125, 256, 0, stream>>>((const unsigned*)h1, rp2, ss, deg, bp1,
      bl1, g1, b1, bm1, bv1, h2, nullptr);
  k_fused<4, false><<<3125, 256, 0, stream>>>((const unsigned*)h2, rp2, ss, deg, bp2,
      bl2, nullptr, nullptr, nullptr, nullptr, nullptr, (float*)d_out);
}

// Round 11
// 599.572 us; speedup vs baseline: 6.0616x; 1.0161x over previous
//
#include <hip/hip_runtime.h>

#define NN 100000
#define NE 1600000
#define DIM 128
#define NT 13            // src tiles: src>>13 -> 8192 rows = 2 MB bf16 per tile (fits 4 MB L2)
#define SH 13
#define LEN (NN * NT)    // bucket counters, tile-major: idx = tt*NN + dst
#define NB_SCAN ((LEN + 1023) / 1024)
#define FST 140          // smF row stride (dwords): 16B-aligned, 2-way banks only
#define CHA 2048         // edges per binning block

typedef __attribute__((ext_vector_type(8))) short short8;
typedef __attribute__((ext_vector_type(4))) float f4;
typedef __attribute__((ext_vector_type(4))) unsigned u4;

__device__ __forceinline__ unsigned short f2bf(float f){
  unsigned x = __float_as_uint(f);
  x += 0x7fffu + ((x >> 16) & 1u);
  return (unsigned short)(x >> 16);
}
__device__ __forceinline__ unsigned pack2(float lo, float hi){
  return ((unsigned)f2bf(hi) << 16) | (unsigned)f2bf(lo);
}
__device__ __forceinline__ float blo(unsigned u){ return __uint_as_float(u << 16); }
__device__ __forceinline__ float bhi(unsigned u){ return __uint_as_float(u & 0xffff0000u); }
__device__ __forceinline__ short8 cvt8(f4 a, f4 b){
  short8 r;
  #pragma unroll
  for (int j = 0; j < 4; ++j){ r[j] = (short)f2bf(a[j]); r[j+4] = (short)f2bf(b[j]); }
  return r;
}

// ---------------- fallback sentinel ----------------
__global__ void k_sentinel(float* __restrict__ out, int n){
  int i = blockIdx.x * blockDim.x + threadIdx.x;
  if (i < n) out[i] = 12345.0f;
}

// ---------------- x fp32 -> bf16x2 ----------------
__global__ void k_cvt(const float* __restrict__ x, unsigned* __restrict__ xb){
  int i = blockIdx.x * blockDim.x + threadIdx.x;   // i < NN*16
  if (i >= NN * 16) return;
  f4 a = ((const f4*)x)[2 * i];
  f4 b = ((const f4*)x)[2 * i + 1];
  u4 o;
  o[0] = pack2(a[0], a[1]); o[1] = pack2(a[2], a[3]);
  o[2] = pack2(b[0], b[1]); o[3] = pack2(b[2], b[3]);
  ((u4*)xb)[i] = o;
}

// ---------------- binning pass 1: count per tile ----------------
__global__ __launch_bounds__(256)
void k_cntA(const int* __restrict__ src, int* __restrict__ gcnt){
  __shared__ int shw[4][16];
  int t = threadIdx.x, lane = t & 63, wv = t >> 6;
  int base0 = blockIdx.x * CHA + wv * (CHA / 4);
  int c[13];
  #pragma unroll
  for (int i = 0; i < 13; ++i) c[i] = 0;
  for (int r = 0; r < CHA / 4 / 64; ++r){
    int idx = base0 + r * 64 + lane;
    int tt = 31;
    if (idx < NE) tt = src[idx] >> SH;
    #pragma unroll
    for (int ti = 0; ti < 13; ++ti)
      c[ti] += __popcll(__ballot(tt == ti));
  }
  #pragma unroll
  for (int ti = 0; ti < 13; ++ti)
    if (lane == ti) shw[wv][ti] = c[ti];
  __syncthreads();
  if (t < 13)
    atomicAdd(&gcnt[t], shw[0][t] + shw[1][t] + shw[2][t] + shw[3][t]);
}

__global__ void k_tscan(const int* __restrict__ gcnt, int* __restrict__ tbase,
                        int* __restrict__ tcur){
  if (threadIdx.x == 0){
    int run = 0;
    for (int i = 0; i < 13; ++i){ tbase[i] = run; tcur[i] = run; run += gcnt[i]; }
    tbase[13] = run;
  }
}

// ---------------- binning pass 2: write to globally-correct tile regions ----
// entry = (dst<<13) | (src&8191). Block reserves per-tile ranges from tcur
// (valid global bases — r10's flaw was reserving before tbase existed).
__global__ __launch_bounds__(256)
void k_binw(const int* __restrict__ src, const int* __restrict__ dst,
            int* __restrict__ tcur, unsigned* __restrict__ binned){
  __shared__ int shw[4][16];
  int t = threadIdx.x, lane = t & 63, wv = t >> 6;
  int base0 = blockIdx.x * CHA + wv * (CHA / 4);
  unsigned long long lt = (1ull << lane) - 1ull;
  int c[13];
  #pragma unroll
  for (int i = 0; i < 13; ++i) c[i] = 0;
  for (int r = 0; r < CHA / 4 / 64; ++r){
    int idx = base0 + r * 64 + lane;
    int tt = 31;
    if (idx < NE) tt = src[idx] >> SH;
    #pragma unroll
    for (int ti = 0; ti < 13; ++ti)
      c[ti] += __popcll(__ballot(tt == ti));
  }
  #pragma unroll
  for (int ti = 0; ti < 13; ++ti)
    if (lane == ti) shw[wv][ti] = c[ti];
  __syncthreads();
  if (t < 13){
    int s = shw[0][t] + shw[1][t] + shw[2][t] + shw[3][t];
    int run = atomicAdd(&tcur[t], s);           // global base for this block's tile-t chunk
    #pragma unroll
    for (int w = 0; w < 4; ++w){ int tmp = shw[w][t]; shw[w][t] = run; run += tmp; }
  }
  __syncthreads();
  int wb[13];
  #pragma unroll
  for (int ti = 0; ti < 13; ++ti) wb[ti] = shw[wv][ti];
  for (int r = 0; r < CHA / 4 / 64; ++r){
    int idx = base0 + r * 64 + lane;
    int tt = 31, s = 0, d = 0;
    if (idx < NE){ s = src[idx]; d = dst[idx]; tt = s >> SH; }
    unsigned entry = ((unsigned)d << 13) | (unsigned)(s & 8191);
    #pragma unroll
    for (int ti = 0; ti < 13; ++ti){
      unsigned long long m = __ballot(tt == ti);
      if (tt == ti) binned[wb[ti] + __popcll(m & lt)] = entry;
      wb[ti] += __popcll(m);
    }
  }
}

// ---------------- histogram over tile-ordered list ----------------
__global__ void k_hist2(const unsigned* __restrict__ binned, const int* __restrict__ tbase,
                        int* __restrict__ cnt){
  __shared__ int tb[14];
  int t = threadIdx.x;
  if (t < 14) tb[t] = tbase[t];
  __syncthreads();
  for (int i = blockIdx.x * 256 + t; i < NE; i += 1024 * 256){
    int tt = 0;
    #pragma unroll
    for (int k = 1; k < 13; ++k) tt += (i >= tb[k]);
    unsigned e = binned[i];
    atomicAdd(&cnt[tt * NN + (int)(e >> 13)], 1);
  }
}

__global__ void k_deg(const int* __restrict__ cnt, int* __restrict__ deg){
  int i = blockIdx.x * blockDim.x + threadIdx.x;
  if (i < NN){
    int s = 0;
    #pragma unroll
    for (int tt = 0; tt < NT; ++tt) s += cnt[tt * NN + i];
    deg[i] = s;
  }
}

__global__ void k_bsum(const int* __restrict__ cnt, int* __restrict__ bsum, int len){
  __shared__ int sh[256];
  int t = threadIdx.x, b = blockIdx.x;
  int base = b * 1024 + t * 4;
  int s = 0;
  #pragma unroll
  for (int j = 0; j < 4; ++j){ int i = base + j; if (i < len) s += cnt[i]; }
  sh[t] = s; __syncthreads();
  for (int off = 128; off > 0; off >>= 1){
    if (t < off) sh[t] += sh[t + off];
    __syncthreads();
  }
  if (t == 0) bsum[b] = sh[0];
}

__global__ void k_scanp(const int* __restrict__ bsum, int* __restrict__ boff, int nb){
  __shared__ int sh[256];
  int t = threadIdx.x;
  int chunk = (nb + 255) / 256;
  int s = 0;
  for (int j = 0; j < chunk; ++j){ int i = t * chunk + j; if (i < nb) s += bsum[i]; }
  sh[t] = s; __syncthreads();
  int tin = s;
  for (int off = 1; off < 256; off <<= 1){
    int u = (t >= off) ? sh[t - off] : 0;
    __syncthreads();
    sh[t] += u;
    __syncthreads();
  }
  int run = sh[t] - tin;
  for (int j = 0; j < chunk; ++j){
    int i = t * chunk + j;
    if (i < nb){ boff[i] = run; run += bsum[i]; }
  }
}

__global__ void k_scanf(const int* __restrict__ cnt, const int* __restrict__ boff,
                        int* __restrict__ rp, int* __restrict__ pos, int len){
  __shared__ int sh[256];
  int t = threadIdx.x, b = blockIdx.x;
  int base = b * 1024 + t * 4;
  int c[4]; int s = 0;
  #pragma unroll
  for (int j = 0; j < 4; ++j){ int i = base + j; c[j] = (i < len) ? cnt[i] : 0; s += c[j]; }
  sh[t] = s; __syncthreads();
  int tin = s;
  for (int off = 1; off < 256; off <<= 1){
    int u = (t >= off) ? sh[t - off] : 0;
    __syncthreads();
    sh[t] += u;
    __syncthreads();
  }
  int run = boff[b] + sh[t] - tin;
  #pragma unroll
  for (int j = 0; j < 4; ++j){
    int i = base + j;
    if (i < len){
      rp[i] = run; pos[i] = run; run += c[j];
      if (i == len - 1) rp[len] = run;
    }
  }
}

// ---------------- scatter to ss16 (tile-local L2 window) ----------------
__global__ void k_binB(const unsigned* __restrict__ binned, const int* __restrict__ tbase,
                       int* __restrict__ pos, unsigned short* __restrict__ ss16){
  __shared__ int tb[14];
  int t = threadIdx.x;
  if (t < 14) tb[t] = tbase[t];
  __syncthreads();
  for (int i = blockIdx.x * 256 + t; i < NE; i += 1024 * 256){
    int tt = 0;
    #pragma unroll
    for (int k = 1; k < 13; ++k) tt += (i >= tb[k]);
    unsigned e = binned[i];
    int d = (int)(e >> 13);
    int p = atomicAdd(&pos[tt * NN + d], 1);
    ss16[p] = (unsigned short)((e & 8191u) | ((unsigned)(d & 7) << 13));
  }
}

// ---------------- W packing ----------------
template<int NB16>
__global__ void k_pack(const float* __restrict__ Wl,
                       const float* __restrict__ Wr,
                       unsigned short* __restrict__ Bp){
  constexpr int DOUT = NB16 * 16;
  int idx = blockIdx.x * blockDim.x + threadIdx.x;
  if (idx >= 8 * NB16 * 64) return;
  int lane = idx & 63;
  int nb = (idx >> 6) % NB16;
  int ks = idx / (64 * NB16);
  int n = nb * 16 + (lane & 15);
  int k0 = ks * 32 + (lane >> 4) * 8;
  short8 v;
  #pragma unroll
  for (int j = 0; j < 8; ++j){
    int k = k0 + j;
    float w = (k < 128) ? Wl[k * DOUT + n] : Wr[(k - 128) * DOUT + n];
    v[j] = (short)f2bf(w);
  }
  ((short8*)Bp)[idx] = v;
}

// ---------------- fused tiled mean-aggregate + dual-GEMM (+BN+ReLU) ----------
template<int NB16, bool DO_BN>
__global__ __launch_bounds__(256)
void k_fused(const unsigned* __restrict__ Xb,
             const int* __restrict__ rp2, const unsigned short* __restrict__ ss16,
             const int* __restrict__ deg,
             const unsigned short* __restrict__ Bp,
             const float* __restrict__ bias,
             const float* __restrict__ bg, const float* __restrict__ bb,
             const float* __restrict__ bm, const float* __restrict__ bv,
             unsigned short* __restrict__ OutB, float* __restrict__ OutF){
  constexpr int DOUT = NB16 * 16;
  constexpr int NBW = NB16 / 4;
  __shared__ float smF[32][FST];
  const int t = threadIdx.x;
  const int lane = t & 63;
  const int wv = t >> 6;
  const int m0 = blockIdx.x * 32;
  const int row0 = m0 + wv * 8;

  for (int i = t; i < 32 * FST; i += 256) (&smF[0][0])[i] = 0.f;
  __syncthreads();

  float* const base = &smF[wv * 8][0];

  int bAll = (lane < NT) ? rp2[lane * NN + row0] : 0;
  int eAll = (lane < NT) ? rp2[lane * NN + row0 + 8] : 0;

  float cx = 0.f, cy = 0.f;
  int cur = 0;

  #define CONS(g, u) {                                        \
    int _r = (g) >> 13;                                       \
    if (_r != cur){                                           \
      float* _p = base + cur * FST + 2 * lane;                \
      _p[0] += cx; _p[1] += cy;                               \
      cx = 0.f; cy = 0.f; cur = _r;                           \
    }                                                         \
    cx += blo(u); cy += bhi(u);                               \
  }

  for (int tt = 0; tt < NT; ++tt){
    int e   = __shfl(bAll, tt);
    int end = __shfl(eAll, tt);
    const unsigned sb = (unsigned)tt << SH;
    for (; e + 8 <= end; e += 8){
      int g0 = __builtin_amdgcn_readfirstlane((int)ss16[e]);
      int g1 = __builtin_amdgcn_readfirstlane((int)ss16[e + 1]);
      int g2 = __builtin_amdgcn_readfirstlane((int)ss16[e + 2]);
      int g3 = __builtin_amdgcn_readfirstlane((int)ss16[e + 3]);
      int g4 = __builtin_amdgcn_readfirstlane((int)ss16[e + 4]);
      int g5 = __builtin_amdgcn_readfirstlane((int)ss16[e + 5]);
      int g6 = __builtin_amdgcn_readfirstlane((int)ss16[e + 6]);
      int g7 = __builtin_amdgcn_readfirstlane((int)ss16[e + 7]);
      unsigned u0 = Xb[(size_t)(sb | (g0 & 8191)) * 64 + lane];
      unsigned u1 = Xb[(size_t)(sb | (g1 & 8191)) * 64 + lane];
      unsigned u2 = Xb[(size_t)(sb | (g2 & 8191)) * 64 + lane];
      unsigned u3 = Xb[(size_t)(sb | (g3 & 8191)) * 64 + lane];
      unsigned u4_ = Xb[(size_t)(sb | (g4 & 8191)) * 64 + lane];
      unsigned u5 = Xb[(size_t)(sb | (g5 & 8191)) * 64 + lane];
      unsigned u6 = Xb[(size_t)(sb | (g6 & 8191)) * 64 + lane];
      unsigned u7 = Xb[(size_t)(sb | (g7 & 8191)) * 64 + lane];
      CONS(g0, u0); CONS(g1, u1); CONS(g2, u2); CONS(g3, u3);
      CONS(g4, u4_); CONS(g5, u5); CONS(g6, u6); CONS(g7, u7);
    }
    for (; e + 4 <= end; e += 4){
      int g0 = __builtin_amdgcn_readfirstlane((int)ss16[e]);
      int g1 = __builtin_amdgcn_readfirstlane((int)ss16[e + 1]);
      int g2 = __builtin_amdgcn_readfirstlane((int)ss16[e + 2]);
      int g3 = __builtin_amdgcn_readfirstlane((int)ss16[e + 3]);
      unsigned u0 = Xb[(size_t)(sb | (g0 & 8191)) * 64 + lane];
      unsigned u1 = Xb[(size_t)(sb | (g1 & 8191)) * 64 + lane];
      unsigned u2 = Xb[(size_t)(sb | (g2 & 8191)) * 64 + lane];
      unsigned u3 = Xb[(size_t)(sb | (g3 & 8191)) * 64 + lane];
      CONS(g0, u0); CONS(g1, u1); CONS(g2, u2); CONS(g3, u3);
    }
    for (; e < end; ++e){
      int g0 = __builtin_amdgcn_readfirstlane((int)ss16[e]);
      unsigned u0 = Xb[(size_t)(sb | (g0 & 8191)) * 64 + lane];
      CONS(g0, u0);
    }
  }
  {
    float* p = base + cur * FST + 2 * lane;
    p[0] += cx; p[1] += cy;
  }
  #undef CONS
  __syncthreads();

  // normalize
  {
    int row = t >> 3;
    int d = deg[m0 + row];
    float inv = (d > 0) ? 1.f / (float)d : 0.f;
    float* pr = &smF[row][(t & 7) * 16];
    #pragma unroll
    for (int i = 0; i < 16; ++i) pr[i] *= inv;
  }
  __syncthreads();

  // ---- phase 2: dual GEMM ----
  const int q = lane >> 4, lr = lane & 15;
  const short8* pb = (const short8*)Bp + lane;
  f4 acc[2][NBW];
  #pragma unroll
  for (int g = 0; g < 2; ++g)
    #pragma unroll
    for (int j = 0; j < NBW; ++j)
      acc[g][j] = (f4){0.f, 0.f, 0.f, 0.f};

  #pragma unroll
  for (int ks = 0; ks < 4; ++ks){
    const float* r0 = &smF[lr][ks * 32 + q * 8];
    const float* r1 = &smF[lr + 16][ks * 32 + q * 8];
    short8 a0 = cvt8(*(const f4*)r0, *(const f4*)(r0 + 4));
    short8 a1 = cvt8(*(const f4*)r1, *(const f4*)(r1 + 4));
    #pragma unroll
    for (int j = 0; j < NBW; ++j){
      int nb = wv * NBW + j;
      short8 b = pb[(ks * NB16 + nb) * 64];
      acc[0][j] = __builtin_amdgcn_mfma_f32_16x16x32_bf16(a0, b, acc[0][j], 0, 0, 0);
      acc[1][j] = __builtin_amdgcn_mfma_f32_16x16x32_bf16(a1, b, acc[1][j], 0, 0, 0);
    }
  }
  #pragma unroll
  for (int ks = 0; ks < 4; ++ks){
    short8 a0 = *(const short8*)(Xb + (size_t)(m0 + lr) * 64 + q*4 + ks*16);
    short8 a1 = *(const short8*)(Xb + (size_t)(m0 + lr + 16) * 64 + q*4 + ks*16);
    #pragma unroll
    for (int j = 0; j < NBW; ++j){
      int nb = wv * NBW + j;
      short8 b = pb[((4 + ks) * NB16 + nb) * 64];
      acc[0][j] = __builtin_amdgcn_mfma_f32_16x16x32_bf16(a0, b, acc[0][j], 0, 0, 0);
      acc[1][j] = __builtin_amdgcn_mfma_f32_16x16x32_bf16(a1, b, acc[1][j], 0, 0, 0);
    }
  }

  // ---- epilogue ----
  #pragma unroll
  for (int j = 0; j < NBW; ++j){
    int col = (wv * NBW + j) * 16 + lr;
    float S = 1.f, T;
    if constexpr (DO_BN){
      float s = bg[col] * rsqrtf(bv[col] + 1e-5f);
      S = s;
      T = (bias[col] - bm[col]) * s + bb[col];
    } else {
      T = bias[col];
    }
    #pragma unroll
    for (int r = 0; r < 4; ++r){
      int row = m0 + q * 4 + r;
      float y0 = acc[0][j][r] * S + T;
      float y1 = acc[1][j][r] * S + T;
      if constexpr (DO_BN){
        y0 = y0 > 0.f ? y0 : 0.f;
        y1 = y1 > 0.f ? y1 : 0.f;
        OutB[(size_t)row * DOUT + col] = f2bf(y0);
        OutB[(size_t)(row + 16) * DOUT + col] = f2bf(y1);
      } else {
        OutF[(size_t)row * DOUT + col] = y0;
        OutF[(size_t)(row + 16) * DOUT + col] = y1;
      }
    }
  }
}

extern "C" void kernel_launch(void* const* d_in, const int* in_sizes, int n_in,
                              void* d_out, int out_size, void* d_ws, size_t ws_size,
                              hipStream_t stream){
  const float* x = (const float*)d_in[0];
  const int* ei = (const int*)d_in[1];
  const float* Wl0 = (const float*)d_in[2];
  const float* Wr0 = (const float*)d_in[3];
  const float* bl0 = (const float*)d_in[4];
  const float* Wl1 = (const float*)d_in[5];
  const float* Wr1 = (const float*)d_in[6];
  const float* bl1 = (const float*)d_in[7];
  const float* Wl2 = (const float*)d_in[8];
  const float* Wr2 = (const float*)d_in[9];
  const float* bl2 = (const float*)d_in[10];
  const float* g0 = (const float*)d_in[11];
  const float* b0 = (const float*)d_in[12];
  const float* bm0 = (const float*)d_in[13];
  const float* bv0 = (const float*)d_in[14];
  const float* g1 = (const float*)d_in[15];
  const float* b1 = (const float*)d_in[16];
  const float* bm1 = (const float*)d_in[17];
  const float* bv1 = (const float*)d_in[18];

  const size_t REQUIRED = 51600000;
  if (ws_size < REQUIRED){
    k_sentinel<<<(out_size + 255) / 256, 256, 0, stream>>>((float*)d_out, out_size);
    return;
  }

  char* w = (char*)d_ws;
  size_t off = 0;
  auto alloc = [&](size_t bytes) -> char* {
    char* p = w + off; off = (off + bytes + 255) & ~(size_t)255; return p;
  };
  int* rp2 = (int*)alloc((size_t)(LEN + 1) * 4);
  unsigned short* ss16 = (unsigned short*)alloc((size_t)NE * 2);
  unsigned* binned = (unsigned*)alloc((size_t)NE * 4);
  unsigned short* bp0 = (unsigned short*)alloc(8 * 8 * 64 * 8 * 2);
  unsigned short* bp1 = (unsigned short*)alloc(8 * 8 * 64 * 8 * 2);
  unsigned short* bp2 = (unsigned short*)alloc(8 * 4 * 64 * 8 * 2);
  unsigned* xb = (unsigned*)alloc((size_t)NN * 64 * 4);   // bf16x2 x; reused as h2
  unsigned short* h2 = (unsigned short*)xb;
  int* cnt2 = (int*)alloc((size_t)LEN * 4);
  int* pos2 = (int*)alloc((size_t)LEN * 4);
  int* deg  = (int*)alloc((size_t)NN * 4);
  int* bsum = (int*)alloc(NB_SCAN * 4);
  int* boff = (int*)alloc(NB_SCAN * 4);
  int* gcnt = (int*)alloc(256);
  int* tbase = (int*)alloc(256);
  int* tcur = (int*)alloc(256);
  unsigned short* h1 = (unsigned short*)d_out;            // 25.6 MB, exactly d_out

  const int* srcI = ei;
  const int* dstI = ei + NE;

  hipMemsetAsync(cnt2, 0, (size_t)LEN * 4, stream);
  hipMemsetAsync(gcnt, 0, 256, stream);
  k_cvt<<<(NN * 16 + 255) / 256, 256, 0, stream>>>(x, xb);
  k_cntA<<<(NE + CHA - 1) / CHA, 256, 0, stream>>>(srcI, gcnt);
  k_tscan<<<1, 64, 0, stream>>>(gcnt, tbase, tcur);
  k_binw<<<(NE + CHA - 1) / CHA, 256, 0, stream>>>(srcI, dstI, tcur, binned);
  k_hist2<<<1024, 256, 0, stream>>>(binned, tbase, cnt2);
  k_deg<<<(NN + 255) / 256, 256, 0, stream>>>(cnt2, deg);
  k_bsum<<<NB_SCAN, 256, 0, stream>>>(cnt2, bsum, LEN);
  k_scanp<<<1, 256, 0, stream>>>(bsum, boff, NB_SCAN);
  k_scanf<<<NB_SCAN, 256, 0, stream>>>(cnt2, boff, rp2, pos2, LEN);
  k_binB<<<1024, 256, 0, stream>>>(binned, tbase, pos2, ss16);
  k_pack<8><<<16, 256, 0, stream>>>(Wl0, Wr0, bp0);
  k_pack<8><<<16, 256, 0, stream>>>(Wl1, Wr1, bp1);
  k_pack<4><<<8, 256, 0, stream>>>(Wl2, Wr2, bp2);

  k_fused<8, true ><<<3125, 256, 0, stream>>>(xb, rp2, ss16, deg, bp0,
      bl0, g0, b0, bm0, bv0, h1, nullptr);
  k_fused<8, true ><<<3125, 256, 0, stream>>>((const unsigned*)h1, rp2, ss16, deg, bp1,
      bl1, g1, b1, bm1, bv1, h2, nullptr);
  k_fused<4, false><<<3125, 256, 0, stream>>>((const unsigned*)h2, rp2, ss16, deg, bp2,
      bl2, nullptr, nullptr, nullptr, nullptr, nullptr, (float*)d_out);
}

// Round 12
// 575.396 us; speedup vs baseline: 6.3163x; 1.0420x over previous
//
#include <hip/hip_runtime.h>

#define NN 100000
#define NE 1600000
#define DIM 128
#define NT 13            // src tiles: src>>13 -> 8192 rows = 2 MB bf16 per tile (fits 4 MB L2)
#define SH 13
#define LEN (NN * NT)    // bucket counters, tile-major: idx = tt*NN + dst
#define NB_SCAN ((LEN + 1023) / 1024)
#define FST 140          // smF row stride (dwords): 16B-aligned, 2-way banks only
#define CHA 2048         // edges per binning block

typedef __attribute__((ext_vector_type(8))) short short8;
typedef __attribute__((ext_vector_type(4))) float f4;
typedef __attribute__((ext_vector_type(4))) unsigned u4;

__device__ __forceinline__ unsigned short f2bf(float f){
  unsigned x = __float_as_uint(f);
  x += 0x7fffu + ((x >> 16) & 1u);
  return (unsigned short)(x >> 16);
}
__device__ __forceinline__ unsigned pack2(float lo, float hi){
  return ((unsigned)f2bf(hi) << 16) | (unsigned)f2bf(lo);
}
__device__ __forceinline__ float blo(unsigned u){ return __uint_as_float(u << 16); }
__device__ __forceinline__ float bhi(unsigned u){ return __uint_as_float(u & 0xffff0000u); }
__device__ __forceinline__ short8 cvt8(f4 a, f4 b){
  short8 r;
  #pragma unroll
  for (int j = 0; j < 4; ++j){ r[j] = (short)f2bf(a[j]); r[j+4] = (short)f2bf(b[j]); }
  return r;
}

// ---------------- fallback sentinel ----------------
__global__ void k_sentinel(float* __restrict__ out, int n){
  int i = blockIdx.x * blockDim.x + threadIdx.x;
  if (i < n) out[i] = 12345.0f;
}

// ---------------- x fp32 -> bf16x2 ----------------
__global__ void k_cvt(const float* __restrict__ x, unsigned* __restrict__ xb){
  int i = blockIdx.x * blockDim.x + threadIdx.x;   // i < NN*16
  if (i >= NN * 16) return;
  f4 a = ((const f4*)x)[2 * i];
  f4 b = ((const f4*)x)[2 * i + 1];
  u4 o;
  o[0] = pack2(a[0], a[1]); o[1] = pack2(a[2], a[3]);
  o[2] = pack2(b[0], b[1]); o[3] = pack2(b[2], b[3]);
  ((u4*)xb)[i] = o;
}

// ---------------- histogram (raw edges -> per (tile,dst) counts) ------------
__global__ void k_hist(const int* __restrict__ src, const int* __restrict__ dst,
                       int* __restrict__ cnt){
  int i = blockIdx.x * blockDim.x + threadIdx.x;
  if (i < NE) atomicAdd(&cnt[(src[i] >> SH) * NN + dst[i]], 1);
}

__global__ void k_deg(const int* __restrict__ cnt, int* __restrict__ deg){
  int i = blockIdx.x * blockDim.x + threadIdx.x;
  if (i < NN){
    int s = 0;
    #pragma unroll
    for (int tt = 0; tt < NT; ++tt) s += cnt[tt * NN + i];
    deg[i] = s;
  }
}

__global__ void k_bsum(const int* __restrict__ cnt, int* __restrict__ bsum, int len){
  __shared__ int sh[256];
  int t = threadIdx.x, b = blockIdx.x;
  int base = b * 1024 + t * 4;
  int s = 0;
  #pragma unroll
  for (int j = 0; j < 4; ++j){ int i = base + j; if (i < len) s += cnt[i]; }
  sh[t] = s; __syncthreads();
  for (int off = 128; off > 0; off >>= 1){
    if (t < off) sh[t] += sh[t + off];
    __syncthreads();
  }
  if (t == 0) bsum[b] = sh[0];
}

__global__ void k_scanp(const int* __restrict__ bsum, int* __restrict__ boff, int nb){
  __shared__ int sh[256];
  int t = threadIdx.x;
  int chunk = (nb + 255) / 256;
  int s = 0;
  for (int j = 0; j < chunk; ++j){ int i = t * chunk + j; if (i < nb) s += bsum[i]; }
  sh[t] = s; __syncthreads();
  int tin = s;
  for (int off = 1; off < 256; off <<= 1){
    int u = (t >= off) ? sh[t - off] : 0;
    __syncthreads();
    sh[t] += u;
    __syncthreads();
  }
  int run = sh[t] - tin;
  for (int j = 0; j < chunk; ++j){
    int i = t * chunk + j;
    if (i < nb){ boff[i] = run; run += bsum[i]; }
  }
}

__global__ void k_scanf(const int* __restrict__ cnt, const int* __restrict__ boff,
                        int* __restrict__ rp, int* __restrict__ pos, int len){
  __shared__ int sh[256];
  int t = threadIdx.x, b = blockIdx.x;
  int base = b * 1024 + t * 4;
  int c[4]; int s = 0;
  #pragma unroll
  for (int j = 0; j < 4; ++j){ int i = base + j; c[j] = (i < len) ? cnt[i] : 0; s += c[j]; }
  sh[t] = s; __syncthreads();
  int tin = s;
  for (int off = 1; off < 256; off <<= 1){
    int u = (t >= off) ? sh[t - off] : 0;
    __syncthreads();
    sh[t] += u;
    __syncthreads();
  }
  int run = boff[b] + sh[t] - tin;
  #pragma unroll
  for (int j = 0; j < 4; ++j){
    int i = base + j;
    if (i < len){
      rp[i] = run; pos[i] = run; run += c[j];
      if (i == len - 1) rp[len] = run;
    }
  }
}

// tbase[tt] = rp2[tt*NN] (tile-region start); tcur = working cursors for k_binw
__global__ void k_tinit(const int* __restrict__ rp2, int* __restrict__ tbase,
                        int* __restrict__ tcur){
  int t = threadIdx.x;
  if (t < 13){ int v = rp2[t * NN]; tbase[t] = v; tcur[t] = v; }
  if (t == 13) tbase[13] = NE;
}

// ---------------- binning: write edges to tile regions (coalesced chunks) ----
// entry = (dst<<13) | (src&8191)
__global__ __launch_bounds__(256)
void k_binw(const int* __restrict__ src, const int* __restrict__ dst,
            int* __restrict__ tcur, unsigned* __restrict__ binned){
  __shared__ int shw[4][16];
  int t = threadIdx.x, lane = t & 63, wv = t >> 6;
  int base0 = blockIdx.x * CHA + wv * (CHA / 4);
  unsigned long long lt = (1ull << lane) - 1ull;
  int c[13];
  #pragma unroll
  for (int i = 0; i < 13; ++i) c[i] = 0;
  for (int r = 0; r < CHA / 4 / 64; ++r){
    int idx = base0 + r * 64 + lane;
    int tt = 31;
    if (idx < NE) tt = src[idx] >> SH;
    #pragma unroll
    for (int ti = 0; ti < 13; ++ti)
      c[ti] += __popcll(__ballot(tt == ti));
  }
  #pragma unroll
  for (int ti = 0; ti < 13; ++ti)
    if (lane == ti) shw[wv][ti] = c[ti];
  __syncthreads();
  if (t < 13){
    int s = shw[0][t] + shw[1][t] + shw[2][t] + shw[3][t];
    int run = atomicAdd(&tcur[t], s);
    #pragma unroll
    for (int w = 0; w < 4; ++w){ int tmp = shw[w][t]; shw[w][t] = run; run += tmp; }
  }
  __syncthreads();
  int wb[13];
  #pragma unroll
  for (int ti = 0; ti < 13; ++ti) wb[ti] = shw[wv][ti];
  for (int r = 0; r < CHA / 4 / 64; ++r){
    int idx = base0 + r * 64 + lane;
    int tt = 31, s = 0, d = 0;
    if (idx < NE){ s = src[idx]; d = dst[idx]; tt = s >> SH; }
    unsigned entry = ((unsigned)d << 13) | (unsigned)(s & 8191);
    #pragma unroll
    for (int ti = 0; ti < 13; ++ti){
      unsigned long long m = __ballot(tt == ti);
      if (tt == ti) binned[wb[ti] + __popcll(m & lt)] = entry;
      wb[ti] += __popcll(m);
    }
  }
}

// ---------------- scatter to ss16 (tile-local L2 window) ----------------
__global__ void k_binB(const unsigned* __restrict__ binned, const int* __restrict__ tbase,
                       int* __restrict__ pos, unsigned short* __restrict__ ss16){
  __shared__ int tb[14];
  int t = threadIdx.x;
  if (t < 14) tb[t] = tbase[t];
  __syncthreads();
  for (int i = blockIdx.x * 256 + t; i < NE; i += 1024 * 256){
    int tt = 0;
    #pragma unroll
    for (int k = 1; k < 13; ++k) tt += (i >= tb[k]);
    unsigned e = binned[i];
    int d = (int)(e >> 13);
    int p = atomicAdd(&pos[tt * NN + d], 1);
    ss16[p] = (unsigned short)((e & 8191u) | ((unsigned)(d & 7) << 13));
  }
}

// ---------------- W packing ----------------
template<int NB16>
__global__ void k_pack(const float* __restrict__ Wl,
                       const float* __restrict__ Wr,
                       unsigned short* __restrict__ Bp){
  constexpr int DOUT = NB16 * 16;
  int idx = blockIdx.x * blockDim.x + threadIdx.x;
  if (idx >= 8 * NB16 * 64) return;
  int lane = idx & 63;
  int nb = (idx >> 6) % NB16;
  int ks = idx / (64 * NB16);
  int n = nb * 16 + (lane & 15);
  int k0 = ks * 32 + (lane >> 4) * 8;
  short8 v;
  #pragma unroll
  for (int j = 0; j < 8; ++j){
    int k = k0 + j;
    float w = (k < 128) ? Wl[k * DOUT + n] : Wr[(k - 128) * DOUT + n];
    v[j] = (short)f2bf(w);
  }
  ((short8*)Bp)[idx] = v;
}

// ---------------- fused tiled mean-aggregate + dual-GEMM (+BN+ReLU) ----------
// e/end made wave-uniform (readfirstlane) so ss16 tag loads scalarize to SMEM
// s_load — halves VMEM issue in the edge loop vs r11.
template<int NB16, bool DO_BN>
__global__ __launch_bounds__(256)
void k_fused(const unsigned* __restrict__ Xb,
             const int* __restrict__ rp2, const unsigned short* __restrict__ ss16,
             const int* __restrict__ deg,
             const unsigned short* __restrict__ Bp,
             const float* __restrict__ bias,
             const float* __restrict__ bg, const float* __restrict__ bb,
             const float* __restrict__ bm, const float* __restrict__ bv,
             unsigned short* __restrict__ OutB, float* __restrict__ OutF){
  constexpr int DOUT = NB16 * 16;
  constexpr int NBW = NB16 / 4;
  __shared__ float smF[32][FST];
  const int t = threadIdx.x;
  const int lane = t & 63;
  const int wv = t >> 6;
  const int m0 = blockIdx.x * 32;
  const int row0 = m0 + wv * 8;

  for (int i = t; i < 32 * FST; i += 256) (&smF[0][0])[i] = 0.f;
  __syncthreads();

  float* const base = &smF[wv * 8][0];

  int bAll = (lane < NT) ? rp2[lane * NN + row0] : 0;
  int eAll = (lane < NT) ? rp2[lane * NN + row0 + 8] : 0;

  float cx = 0.f, cy = 0.f;
  int cur = 0;

  #define CONS(g, u) {                                        \
    int _r = (g) >> 13;                                       \
    if (_r != cur){                                           \
      float* _p = base + cur * FST + 2 * lane;                \
      _p[0] += cx; _p[1] += cy;                               \
      cx = 0.f; cy = 0.f; cur = _r;                           \
    }                                                         \
    cx += blo(u); cy += bhi(u);                               \
  }

  for (int tt = 0; tt < NT; ++tt){
    int e   = __builtin_amdgcn_readfirstlane(__shfl(bAll, tt));
    int end = __builtin_amdgcn_readfirstlane(__shfl(eAll, tt));
    const unsigned sb = (unsigned)tt << SH;
    for (; e + 8 <= end; e += 8){
      int g0 = __builtin_amdgcn_readfirstlane((int)ss16[e]);
      int g1 = __builtin_amdgcn_readfirstlane((int)ss16[e + 1]);
      int g2 = __builtin_amdgcn_readfirstlane((int)ss16[e + 2]);
      int g3 = __builtin_amdgcn_readfirstlane((int)ss16[e + 3]);
      int g4 = __builtin_amdgcn_readfirstlane((int)ss16[e + 4]);
      int g5 = __builtin_amdgcn_readfirstlane((int)ss16[e + 5]);
      int g6 = __builtin_amdgcn_readfirstlane((int)ss16[e + 6]);
      int g7 = __builtin_amdgcn_readfirstlane((int)ss16[e + 7]);
      unsigned u0 = Xb[(size_t)(sb | (g0 & 8191)) * 64 + lane];
      unsigned u1 = Xb[(size_t)(sb | (g1 & 8191)) * 64 + lane];
      unsigned u2 = Xb[(size_t)(sb | (g2 & 8191)) * 64 + lane];
      unsigned u3 = Xb[(size_t)(sb | (g3 & 8191)) * 64 + lane];
      unsigned u4_ = Xb[(size_t)(sb | (g4 & 8191)) * 64 + lane];
      unsigned u5 = Xb[(size_t)(sb | (g5 & 8191)) * 64 + lane];
      unsigned u6 = Xb[(size_t)(sb | (g6 & 8191)) * 64 + lane];
      unsigned u7 = Xb[(size_t)(sb | (g7 & 8191)) * 64 + lane];
      CONS(g0, u0); CONS(g1, u1); CONS(g2, u2); CONS(g3, u3);
      CONS(g4, u4_); CONS(g5, u5); CONS(g6, u6); CONS(g7, u7);
    }
    for (; e + 4 <= end; e += 4){
      int g0 = __builtin_amdgcn_readfirstlane((int)ss16[e]);
      int g1 = __builtin_amdgcn_readfirstlane((int)ss16[e + 1]);
      int g2 = __builtin_amdgcn_readfirstlane((int)ss16[e + 2]);
      int g3 = __builtin_amdgcn_readfirstlane((int)ss16[e + 3]);
      unsigned u0 = Xb[(size_t)(sb | (g0 & 8191)) * 64 + lane];
      unsigned u1 = Xb[(size_t)(sb | (g1 & 8191)) * 64 + lane];
      unsigned u2 = Xb[(size_t)(sb | (g2 & 8191)) * 64 + lane];
      unsigned u3 = Xb[(size_t)(sb | (g3 & 8191)) * 64 + lane];
      CONS(g0, u0); CONS(g1, u1); CONS(g2, u2); CONS(g3, u3);
    }
    for (; e < end; ++e){
      int g0 = __builtin_amdgcn_readfirstlane((int)ss16[e]);
      unsigned u0 = Xb[(size_t)(sb | (g0 & 8191)) * 64 + lane];
      CONS(g0, u0);
    }
  }
  {
    float* p = base + cur * FST + 2 * lane;
    p[0] += cx; p[1] += cy;
  }
  #undef CONS
  __syncthreads();

  // normalize
  {
    int row = t >> 3;
    int d = deg[m0 + row];
    float inv = (d > 0) ? 1.f / (float)d : 0.f;
    float* pr = &smF[row][(t & 7) * 16];
    #pragma unroll
    for (int i = 0; i < 16; ++i) pr[i] *= inv;
  }
  __syncthreads();

  // ---- phase 2: dual GEMM ----
  const int q = lane >> 4, lr = lane & 15;
  const short8* pb = (const short8*)Bp + lane;
  f4 acc[2][NBW];
  #pragma unroll
  for (int g = 0; g < 2; ++g)
    #pragma unroll
    for (int j = 0; j < NBW; ++j)
      acc[g][j] = (f4){0.f, 0.f, 0.f, 0.f};

  #pragma unroll
  for (int ks = 0; ks < 4; ++ks){
    const float* r0 = &smF[lr][ks * 32 + q * 8];
    const float* r1 = &smF[lr + 16][ks * 32 + q * 8];
    short8 a0 = cvt8(*(const f4*)r0, *(const f4*)(r0 + 4));
    short8 a1 = cvt8(*(const f4*)r1, *(const f4*)(r1 + 4));
    #pragma unroll
    for (int j = 0; j < NBW; ++j){
      int nb = wv * NBW + j;
      short8 b = pb[(ks * NB16 + nb) * 64];
      acc[0][j] = __builtin_amdgcn_mfma_f32_16x16x32_bf16(a0, b, acc[0][j], 0, 0, 0);
      acc[1][j] = __builtin_amdgcn_mfma_f32_16x16x32_bf16(a1, b, acc[1][j], 0, 0, 0);
    }
  }
  #pragma unroll
  for (int ks = 0; ks < 4; ++ks){
    short8 a0 = *(const short8*)(Xb + (size_t)(m0 + lr) * 64 + q*4 + ks*16);
    short8 a1 = *(const short8*)(Xb + (size_t)(m0 + lr + 16) * 64 + q*4 + ks*16);
    #pragma unroll
    for (int j = 0; j < NBW; ++j){
      int nb = wv * NBW + j;
      short8 b = pb[((4 + ks) * NB16 + nb) * 64];
      acc[0][j] = __builtin_amdgcn_mfma_f32_16x16x32_bf16(a0, b, acc[0][j], 0, 0, 0);
      acc[1][j] = __builtin_amdgcn_mfma_f32_16x16x32_bf16(a1, b, acc[1][j], 0, 0, 0);
    }
  }

  // ---- epilogue ----
  #pragma unroll
  for (int j = 0; j < NBW; ++j){
    int col = (wv * NBW + j) * 16 + lr;
    float S = 1.f, T;
    if constexpr (DO_BN){
      float s = bg[col] * rsqrtf(bv[col] + 1e-5f);
      S = s;
      T = (bias[col] - bm[col]) * s + bb[col];
    } else {
      T = bias[col];
    }
    #pragma unroll
    for (int r = 0; r < 4; ++r){
      int row = m0 + q * 4 + r;
      float y0 = acc[0][j][r] * S + T;
      float y1 = acc[1][j][r] * S + T;
      if constexpr (DO_BN){
        y0 = y0 > 0.f ? y0 : 0.f;
        y1 = y1 > 0.f ? y1 : 0.f;
        OutB[(size_t)row * DOUT + col] = f2bf(y0);
        OutB[(size_t)(row + 16) * DOUT + col] = f2bf(y1);
      } else {
        OutF[(size_t)row * DOUT + col] = y0;
        OutF[(size_t)(row + 16) * DOUT + col] = y1;
      }
    }
  }
}

extern "C" void kernel_launch(void* const* d_in, const int* in_sizes, int n_in,
                              void* d_out, int out_size, void* d_ws, size_t ws_size,
                              hipStream_t stream){
  const float* x = (const float*)d_in[0];
  const int* ei = (const int*)d_in[1];
  const float* Wl0 = (const float*)d_in[2];
  const float* Wr0 = (const float*)d_in[3];
  const float* bl0 = (const float*)d_in[4];
  const float* Wl1 = (const float*)d_in[5];
  const float* Wr1 = (const float*)d_in[6];
  const float* bl1 = (const float*)d_in[7];
  const float* Wl2 = (const float*)d_in[8];
  const float* Wr2 = (const float*)d_in[9];
  const float* bl2 = (const float*)d_in[10];
  const float* g0 = (const float*)d_in[11];
  const float* b0 = (const float*)d_in[12];
  const float* bm0 = (const float*)d_in[13];
  const float* bv0 = (const float*)d_in[14];
  const float* g1 = (const float*)d_in[15];
  const float* b1 = (const float*)d_in[16];
  const float* bm1 = (const float*)d_in[17];
  const float* bv1 = (const float*)d_in[18];

  const size_t REQUIRED = 51600000;
  if (ws_size < REQUIRED){
    k_sentinel<<<(out_size + 255) / 256, 256, 0, stream>>>((float*)d_out, out_size);
    return;
  }

  char* w = (char*)d_ws;
  size_t off = 0;
  auto alloc = [&](size_t bytes) -> char* {
    char* p = w + off; off = (off + bytes + 255) & ~(size_t)255; return p;
  };
  int* rp2 = (int*)alloc((size_t)(LEN + 1) * 4);
  unsigned short* ss16 = (unsigned short*)alloc((size_t)NE * 2);
  unsigned* binned = (unsigned*)alloc((size_t)NE * 4);
  unsigned short* bp0 = (unsigned short*)alloc(8 * 8 * 64 * 8 * 2);
  unsigned short* bp1 = (unsigned short*)alloc(8 * 8 * 64 * 8 * 2);
  unsigned short* bp2 = (unsigned short*)alloc(8 * 4 * 64 * 8 * 2);
  unsigned* xb = (unsigned*)alloc((size_t)NN * 64 * 4);   // bf16x2 x; reused as h2
  unsigned short* h2 = (unsigned short*)xb;
  int* cnt2 = (int*)alloc((size_t)LEN * 4);
  int* pos2 = (int*)alloc((size_t)LEN * 4);
  int* deg  = (int*)alloc((size_t)NN * 4);
  int* bsum = (int*)alloc(NB_SCAN * 4);
  int* boff = (int*)alloc(NB_SCAN * 4);
  int* tbase = (int*)alloc(256);
  int* tcur = (int*)alloc(256);
  unsigned short* h1 = (unsigned short*)d_out;            // 25.6 MB, exactly d_out

  const int* srcI = ei;
  const int* dstI = ei + NE;

  hipMemsetAsync(cnt2, 0, (size_t)LEN * 4, stream);
  k_cvt<<<(NN * 16 + 255) / 256, 256, 0, stream>>>(x, xb);
  k_hist<<<(NE + 255) / 256, 256, 0, stream>>>(srcI, dstI, cnt2);
  k_deg<<<(NN + 255) / 256, 256, 0, stream>>>(cnt2, deg);
  k_bsum<<<NB_SCAN, 256, 0, stream>>>(cnt2, bsum, LEN);
  k_scanp<<<1, 256, 0, stream>>>(bsum, boff, NB_SCAN);
  k_scanf<<<NB_SCAN, 256, 0, stream>>>(cnt2, boff, rp2, pos2, LEN);
  k_tinit<<<1, 64, 0, stream>>>(rp2, tbase, tcur);
  k_binw<<<(NE + CHA - 1) / CHA, 256, 0, stream>>>(srcI, dstI, tcur, binned);
  k_binB<<<1024, 256, 0, stream>>>(binned, tbase, pos2, ss16);
  k_pack<8><<<16, 256, 0, stream>>>(Wl0, Wr0, bp0);
  k_pack<8><<<16, 256, 0, stream>>>(Wl1, Wr1, bp1);
  k_pack<4><<<8, 256, 0, stream>>>(Wl2, Wr2, bp2);

  k_fused<8, true ><<<3125, 256, 0, stream>>>(xb, rp2, ss16, deg, bp0,
      bl0, g0, b0, bm0, bv0, h1, nullptr);
  k_fused<8, true ><<<3125, 256, 0, stream>>>((const unsigned*)h1, rp2, ss16, deg, bp1,
      bl1, g1, b1, bm1, bv1, h2, nullptr);
  k_fused<4, false><<<3125, 256, 0, stream>>>((const unsigned*)h2, rp2, ss16, deg, bp2,
      bl2, nullptr, nullptr, nullptr, nullptr, nullptr, (float*)d_out);
}